// Round 3
// baseline (741.719 us; speedup 1.0000x reference)
//
#include <hip/hip_runtime.h>
#include <hip/hip_bf16.h>

using bf16 = __hip_bfloat16;
typedef __bf16 bf16x8 __attribute__((ext_vector_type(8)));
typedef __bf16 bf16x4 __attribute__((ext_vector_type(4)));
typedef float  f32x4  __attribute__((ext_vector_type(4)));

#define B_ 8
#define S_ 2048
#define H_ 1024
#define M_ (B_ * S_)   // 16384
#define N_ (2 * H_)    // 2048
#define K_ 1024
#define CHUNKS_ 32
#define CLEN_ 64       // 32*64 = 2048 = S_

__device__ __forceinline__ bf16x8 load8f(const float* p) {
  const float4 a = *(const float4*)p;
  const float4 b = *(const float4*)(p + 4);
  bf16x8 r;
  r[0] = (__bf16)a.x; r[1] = (__bf16)a.y; r[2] = (__bf16)a.z; r[3] = (__bf16)a.w;
  r[4] = (__bf16)b.x; r[5] = (__bf16)b.y; r[6] = (__bf16)b.z; r[7] = (__bf16)b.w;
  return r;
}

// f32 -> bf16 bulk convert, 8 elems/thread. n must be multiple of 8.
__global__ __launch_bounds__(256)
void cvt_f32_bf16(const float* __restrict__ src, bf16* __restrict__ dst, long n) {
  const long i = ((long)blockIdx.x * 256 + threadIdx.x) * 8;
  if (i >= n) return;
  *(bf16x8*)(dst + i) = load8f(src + i);
}

// ---------------------------------------------------------------------------
// Fallback GEMM (narrow-workspace path only): m97-style 128x128 tile.
// ---------------------------------------------------------------------------
template <bool WDMA>
__global__ __launch_bounds__(256)
void gemm_bias(const bf16* __restrict__ A, const bf16* __restrict__ Wb,
               const float* __restrict__ Wf, const float* __restrict__ bias,
               bf16* __restrict__ C) {
  __shared__ __align__(16) char lds[16384];
  const int tid  = threadIdx.x;
  const int lane = tid & 63;
  const int wv   = tid >> 6;
  const int wr   = wv >> 1;
  const int wc   = wv & 1;
  const int r15  = lane & 15;
  const int kq   = lane >> 4;
  const int mBase = blockIdx.y * 128;
  const int nBase = blockIdx.x * 128;

  f32x4 acc[4][4];
#pragma unroll
  for (int i = 0; i < 4; ++i)
#pragma unroll
    for (int j = 0; j < 4; ++j)
#pragma unroll
      for (int r = 0; r < 4; ++r) acc[i][j][r] = 0.0f;

  for (int k0 = 0; k0 < K_; k0 += 32) {
    bf16x8 sw[2];
    if constexpr (!WDMA) {
#pragma unroll
      for (int c = 0; c < 2; ++c) {
        const int seg = wv * 2 + c;
        sw[c] = load8f(Wf + (size_t)(nBase + seg * 16 + r15) * K_ + k0 + kq * 8);
      }
    }
    __syncthreads();
#pragma unroll
    for (int c = 0; c < 2; ++c) {
      const int seg = wv * 2 + c;
      const bf16* ga = A + (size_t)(mBase + seg * 16 + r15) * K_ + k0 + kq * 8;
      __builtin_amdgcn_global_load_lds(
          (const __attribute__((address_space(1))) void*)ga,
          (__attribute__((address_space(3))) void*)(lds + seg * 1024), 16, 0, 0);
      if constexpr (WDMA) {
        const bf16* gw = Wb + (size_t)(nBase + seg * 16 + r15) * K_ + k0 + kq * 8;
        __builtin_amdgcn_global_load_lds(
            (const __attribute__((address_space(1))) void*)gw,
            (__attribute__((address_space(3))) void*)(lds + 8192 + seg * 1024), 16, 0, 0);
      } else {
        *(bf16x8*)(lds + 8192 + seg * 1024 + lane * 16) = sw[c];
      }
    }
    __syncthreads();

    bf16x8 af[4], bfr[4];
#pragma unroll
    for (int i = 0; i < 4; ++i)
      af[i] = *(const bf16x8*)(lds + (wr * 4 + i) * 1024 + lane * 16);
#pragma unroll
    for (int j = 0; j < 4; ++j)
      bfr[j] = *(const bf16x8*)(lds + 8192 + (wc * 4 + j) * 1024 + lane * 16);
#pragma unroll
    for (int i = 0; i < 4; ++i)
#pragma unroll
      for (int j = 0; j < 4; ++j)
        acc[i][j] = __builtin_amdgcn_mfma_f32_16x16x32_bf16(af[i], bfr[j],
                                                            acc[i][j], 0, 0, 0);
  }

#pragma unroll
  for (int j = 0; j < 4; ++j) {
    const int col = nBase + wc * 64 + j * 16 + r15;
    const float bv = bias[col];
#pragma unroll
    for (int i = 0; i < 4; ++i) {
      const int row = mBase + wr * 64 + i * 16 + kq * 4;
#pragma unroll
      for (int r = 0; r < 4; ++r)
        C[(size_t)(row + r) * N_ + col] = __float2bfloat16(acc[i][j][r] + bv);
    }
  }
}

// ---------------------------------------------------------------------------
// 256x256 8-phase GEMM (wide path): C[m][n] = sum_k A[m][k]*W[n][k] + bias[n]
// T1 XCD swizzle + T2 XOR-swizzled LDS + T3/T4 8-phase counted-vmcnt + T5.
// (Unchanged from round 2: 76.5 us, MfmaUtil 37%, FETCH 49 MB, 0 bank conf.)
//
// Geometry: BM=BN=256, BK=64, 8 waves (2M x 4N), per-wave output 128x64,
// acc = f32x4[8][4]. LDS 128 KiB = 2 buffers x {A[2 halves][128x64 bf16],
// B[2 halves][128x64 bf16]}; half-tile = 16 KiB staged by 2 global_load_lds
// per thread (512 thr x 2 x 16B).
//
// T2 swizzle (involution on 16B chunks within a half-tile, row stride 128B):
//   phys_byte = logical_byte ^ ((row & 7) << 4),  row = logical_byte >> 7.
// Staging keeps LDS dest linear (gload_lds HW constraint) and pre-swizzles
// the per-lane GLOBAL source chunk: src_chunk = t ^ ((t>>3)&7).  Fragment
// ds_read_b128 applies the same XOR => lanes 0-15 (rows 0-15, fixed col)
// land on distinct bank-quads, 2-way (free) instead of 16-way.
//
// Phase ledger per iteration (tiles t in buf0 = phases P1-4, t+1 in buf1 =
// P5-8; one half-tile stage per phase; slot is free only after the last
// phase that ds_reads it -- B halves after P2, A halves after P3):
//   P1: ds A0-3,B0-1 (12) stage t+1.A1   P5: ds A0-3,B0-1  stage t+2.A1
//   P2: ds B2-3      (4)  stage t+1.B1   P6: ds B2-3       stage t+2.B1
//   P3: ds A4-7      (8)  stage t+2.B0   P7: ds A4-7       stage t+3.B0
//   P4: --                stage t+2.A0   P8: --            stage t+3.A0
//   vmcnt(4) at end of P4/P8: 6 stages (12 loads) in flight, oldest 4 stages
//   (= next tile complete) must land, newest 2 (4 loads) may remain.
// ---------------------------------------------------------------------------
#define BK_    64
#define NT_    (K_ / BK_)   // 16
#define LBUF_  65536
#define LBOFF_ 32768
#define LHALF_ 16384

__global__ __launch_bounds__(512, 2)
void gemm256(const bf16* __restrict__ A, const bf16* __restrict__ W,
             const float* __restrict__ bias, bf16* __restrict__ C) {
  __shared__ __align__(16) char lds[131072];
  const int tid  = threadIdx.x;
  const int lane = tid & 63;
  const int wv   = tid >> 6;   // 0..7
  const int wm   = wv >> 2;    // 0..1  (row half)
  const int wn   = wv & 3;     // 0..3  (64-col strip)
  const int r15  = lane & 15;
  const int kq   = lane >> 4;

  // T1: bijective XCD swizzle. nwg=512, 512%8==0. XCD x = flat%8 gets
  // sw in [x*64, x*64+64) -> row panels [8x,8x+8) x all 8 col tiles:
  // A panels become XCD-local in L2.
  const int flat = blockIdx.x;
  const int sw   = (flat & 7) * 64 + (flat >> 3);
  const int by   = sw >> 3;    // 0..63
  const int bx   = sw & 7;     // 0..7
  const int mBase = by * 256;
  const int nBase = bx * 256;

  // staging: per-thread loop-invariant source/dest offsets
  size_t srcOff[2];
  int dstOff[2];
#pragma unroll
  for (int q = 0; q < 2; ++q) {
    const int t  = q * 512 + tid;                 // 16B chunk id 0..1023
    const int cc = (t & 7) ^ ((t >> 3) & 7);      // pre-swizzled col chunk
    srcOff[q] = (size_t)(t >> 3) * K_ + cc * 8;   // elements
    dstOff[q] = q * 8192 + wv * 1024;             // linear LDS bytes (wave-uniform)
  }
  const bf16* aH[2] = {A + (size_t)mBase * K_, A + (size_t)(mBase + 128) * K_};
  const bf16* wH[2] = {W + (size_t)nBase * K_, W + (size_t)(nBase + 128) * K_};

#define STAGE(GB, LOFF)                                                        \
  { _Pragma("unroll") for (int q_ = 0; q_ < 2; ++q_)                           \
      __builtin_amdgcn_global_load_lds(                                        \
          (const __attribute__((address_space(1))) void*)((GB) + srcOff[q_]),  \
          (__attribute__((address_space(3))) void*)(lds + (LOFF) + dstOff[q_]),\
          16, 0, 0); }

  // fragment read offsets (T2 read-side XOR; row&7 == r15&7)
  const int xsw  = (r15 & 7) << 4;
  const int col0 = (kq * 16) ^ xsw;
  const int col1 = (64 + kq * 16) ^ xsw;
  const int aRow = wm * LHALF_ + r15 * 128;
  const int bRow = LBOFF_ + (wn >> 1) * LHALF_ + ((wn & 1) * 64 + r15) * 128;

  f32x4 acc[8][4];
#pragma unroll
  for (int i = 0; i < 8; ++i)
#pragma unroll
    for (int j = 0; j < 4; ++j)
#pragma unroll
      for (int r = 0; r < 4; ++r) acc[i][j][r] = 0.0f;

  bf16x8 aF[4][2], bF[4][2];

#define LD_A(BO)                                                               \
  { _Pragma("unroll") for (int i_ = 0; i_ < 4; ++i_) {                         \
      aF[i_][0] = *(const bf16x8*)(lds + (BO) + i_ * 2048 + col0);             \
      aF[i_][1] = *(const bf16x8*)(lds + (BO) + i_ * 2048 + col1); } }
  // BO carries aRow (+ 8192 for rows 64..127)

#define LD_B(J0, BO)                                                           \
  { _Pragma("unroll") for (int j_ = 0; j_ < 2; ++j_) {                         \
      bF[(J0) + j_][0] =                                                       \
          *(const bf16x8*)(lds + (BO) + bRow + ((J0) + j_) * 2048 + col0);     \
      bF[(J0) + j_][1] =                                                       \
          *(const bf16x8*)(lds + (BO) + bRow + ((J0) + j_) * 2048 + col1); } }

#define MFMA_Q(I0, J0)                                                         \
  { _Pragma("unroll") for (int i_ = 0; i_ < 4; ++i_)                           \
    _Pragma("unroll") for (int j_ = 0; j_ < 2; ++j_)                           \
    _Pragma("unroll") for (int k_ = 0; k_ < 2; ++k_)                           \
      acc[(I0) + i_][(J0) + j_] = __builtin_amdgcn_mfma_f32_16x16x32_bf16(     \
          aF[i_][k_], bF[(J0) + j_][k_], acc[(I0) + i_][(J0) + j_], 0, 0, 0); }

#define PH_BAR()                                                               \
  __builtin_amdgcn_sched_barrier(0);                                           \
  __builtin_amdgcn_s_barrier();                                                \
  asm volatile("s_waitcnt lgkmcnt(0)" ::: "memory");                           \
  __builtin_amdgcn_sched_barrier(0);                                           \
  __builtin_amdgcn_s_setprio(1);

#define PH_END()                                                               \
  __builtin_amdgcn_s_setprio(0);                                               \
  __builtin_amdgcn_sched_barrier(0);                                           \
  __builtin_amdgcn_s_barrier();

#define PH_END_VM(N)                                                           \
  __builtin_amdgcn_s_setprio(0);                                               \
  __builtin_amdgcn_sched_barrier(0);                                           \
  asm volatile("s_waitcnt vmcnt(" #N ")" ::: "memory");                        \
  __builtin_amdgcn_s_barrier();

  // Prologue: tile0 complete + t1.{B0,A0} in flight (matches steady state).
  STAGE(aH[0], 0);
  STAGE(aH[1], LHALF_);
  STAGE(wH[0], LBOFF_);
  STAGE(wH[1], LBOFF_ + LHALF_);
  STAGE(wH[0] + BK_, LBUF_ + LBOFF_);
  STAGE(aH[0] + BK_, LBUF_);
  asm volatile("s_waitcnt vmcnt(4)" ::: "memory");
  __builtin_amdgcn_s_barrier();

#pragma unroll 1
  for (int t = 0; t < NT_ - 2; t += 2) {
    const int o1 = (t + 1) * BK_, o2 = (t + 2) * BK_, o3 = (t + 3) * BK_;
    // ---- tile t (buf0) ----
    LD_A(aRow); LD_B(0, 0);
    STAGE(aH[1] + o1, LBUF_ + LHALF_);             // t+1.A1
    asm volatile("s_waitcnt lgkmcnt(8)" ::: "memory");
    PH_BAR(); MFMA_Q(0, 0); PH_END();
    LD_B(2, 0);
    STAGE(wH[1] + o1, LBUF_ + LBOFF_ + LHALF_);    // t+1.B1
    PH_BAR(); MFMA_Q(0, 2); PH_END();
    LD_A(aRow + 8192);
    STAGE(wH[0] + o2, LBOFF_);                     // t+2.B0 (buf0.B0 free after P2)
    PH_BAR(); MFMA_Q(4, 0); PH_END();
    STAGE(aH[0] + o2, 0);                          // t+2.A0 (buf0.A0 free after P3)
    PH_BAR(); MFMA_Q(4, 2); PH_END_VM(4);          // t+1 landed, 4 loads in flight
    // ---- tile t+1 (buf1) ----
    LD_A(LBUF_ + aRow); LD_B(0, LBUF_);
    STAGE(aH[1] + o2, LHALF_);                     // t+2.A1
    asm volatile("s_waitcnt lgkmcnt(8)" ::: "memory");
    PH_BAR(); MFMA_Q(0, 0); PH_END();
    LD_B(2, LBUF_);
    STAGE(wH[1] + o2, LBOFF_ + LHALF_);            // t+2.B1
    PH_BAR(); MFMA_Q(0, 2); PH_END();
    LD_A(LBUF_ + aRow + 8192);
    STAGE(wH[0] + o3, LBUF_ + LBOFF_);             // t+3.B0
    PH_BAR(); MFMA_Q(4, 0); PH_END();
    STAGE(aH[0] + o3, LBUF_);                      // t+3.A0
    PH_BAR(); MFMA_Q(4, 2); PH_END_VM(4);          // t+2 landed
  }

  // Tail: tiles 14 (buf0) and 15 (buf1); only t15.{A1,B1} left to stage.
  {
    const int o1 = (NT_ - 1) * BK_;
    LD_A(aRow); LD_B(0, 0);
    STAGE(aH[1] + o1, LBUF_ + LHALF_);             // t15.A1
    asm volatile("s_waitcnt lgkmcnt(8)" ::: "memory");
    PH_BAR(); MFMA_Q(0, 0); PH_END();
    LD_B(2, 0);
    STAGE(wH[1] + o1, LBUF_ + LBOFF_ + LHALF_);    // t15.B1
    PH_BAR(); MFMA_Q(0, 2); PH_END();
    LD_A(aRow + 8192);
    PH_BAR(); MFMA_Q(4, 0); PH_END();
    PH_BAR(); MFMA_Q(4, 2); PH_END_VM(0);          // t15 fully landed
    // tile 15, no stages
    LD_A(LBUF_ + aRow); LD_B(0, LBUF_);
    PH_BAR(); MFMA_Q(0, 0); PH_END();
    LD_B(2, LBUF_);
    PH_BAR(); MFMA_Q(0, 2); PH_END();
    LD_A(LBUF_ + aRow + 8192);
    PH_BAR(); MFMA_Q(4, 0); PH_END();
    PH_BAR(); MFMA_Q(4, 2);
    __builtin_amdgcn_s_setprio(0);
  }

  // Epilogue. C/D layout: col = lane&15, row = (lane>>4)*4 + r (r3-verified).
#pragma unroll
  for (int j = 0; j < 4; ++j) {
    const int col = nBase + wn * 64 + j * 16 + r15;
    const float bv = bias[col];
#pragma unroll
    for (int i = 0; i < 8; ++i) {
      const int row0 = mBase + wm * 128 + i * 16 + kq * 4;
#pragma unroll
      for (int r = 0; r < 4; ++r)
        C[(size_t)(row0 + r) * N_ + col] = __float2bfloat16(acc[i][j][r] + bv);
    }
  }
#undef STAGE
#undef LD_A
#undef LD_B
#undef MFMA_Q
#undef PH_BAR
#undef PH_END
#undef PH_END_VM
}

// ---------------------------------------------------------------------------
// Scan pointwise math:  h_t = ca*h_{t-1} + cb
//   ca = 1 - z = 1/(1+exp(gate));  cb = z * g(hidden)
//   g(x) = x + 0.5 (x>=0) else sigmoid(x)
// ---------------------------------------------------------------------------
__device__ __forceinline__ float rcpf(float x) { return __builtin_amdgcn_rcpf(x); }

__device__ __forceinline__ void step_coeffs(float gate, float hidden,
                                            float& ca, float& cb) {
  const float e1 = __expf(gate);
  ca = rcpf(1.0f + e1);
  const float z = 1.0f - ca;
  float g;
  if (hidden >= 0.0f) {
    g = hidden + 0.5f;
  } else {
    const float e2 = __expf(hidden);
    g = e2 * rcpf(1.0f + e2);
  }
  cb = z * g;
}

__device__ __forceinline__ float g_of(float x) {
  if (x >= 0.0f) return x + 0.5f;
  const float e = __expf(x);
  return e * rcpf(1.0f + e);
}

// Phase A: per (channel, chunk) composed affine (A,B): h_out = A*h_in + B.
// 4 channels/thread, bf16x4 loads (8B/lane, 512B/wave contiguous).
// Grid: 256 blocks x 256 thr; block = (chunk j = bx>>3, batch b = bx&7),
// thread covers channels h = tx*4 .. tx*4+3 of batch b.
__global__ __launch_bounds__(256)
void scan_chunk(const bf16* __restrict__ gh, float2* __restrict__ sAB) {
  const int tx = threadIdx.x, bx = blockIdx.x;
  const int b = bx & 7, j = bx >> 3;
  const int h = tx * 4;
  const int c = b * 1024 + h;
  const bf16* gbase = gh + ((size_t)(b * S_ + j * CLEN_)) * N_ + h;
  float A[4] = {1.0f, 1.0f, 1.0f, 1.0f};
  float Bc[4] = {0.0f, 0.0f, 0.0f, 0.0f};
#pragma unroll 4
  for (int t = 0; t < CLEN_; ++t) {
    const bf16x4 gv = *(const bf16x4*)(gbase + (size_t)t * N_);
    const bf16x4 hv = *(const bf16x4*)(gbase + (size_t)t * N_ + H_);
#pragma unroll
    for (int q = 0; q < 4; ++q) {
      float ca, cb;
      step_coeffs((float)gv[q], (float)hv[q], ca, cb);
      A[q] *= ca;
      Bc[q] = ca * Bc[q] + cb;
    }
  }
  float2* o = sAB + (size_t)j * (B_ * H_) + c;
  *(float4*)(o)     = make_float4(A[0], Bc[0], A[1], Bc[1]);
  *(float4*)(o + 2) = make_float4(A[2], Bc[2], A[3], Bc[3]);
}

// Phase B+C fused: each block recomputes its chunk's carry by walking the
// sAB prefix [0, j) for its 4 channels (bit-identical order to the old
// scan_carry), then applies the chunk. 4 channels/thread, all vector
// memory ops. rin may alias rout (element-wise read-before-write per t).
__global__ __launch_bounds__(256)
void scan_apply(const bf16* __restrict__ gh, const float2* __restrict__ sAB,
                const float* __restrict__ hprev,
                const float* rin, float* rout, bf16* gout,
                float* __restrict__ finals) {
  const int tx = threadIdx.x, bx = blockIdx.x;
  const int b = bx & 7, j = bx >> 3;
  const int h = tx * 4;
  const int c = b * 1024 + h;

  float hr[4];
  {
    const float4 hp = *(const float4*)(hprev + c);
    hr[0] = g_of(hp.x); hr[1] = g_of(hp.y);
    hr[2] = g_of(hp.z); hr[3] = g_of(hp.w);
  }
  for (int jj = 0; jj < j; ++jj) {
    const float2* s = sAB + (size_t)jj * (B_ * H_) + c;
    const float4 ab01 = *(const float4*)(s);
    const float4 ab23 = *(const float4*)(s + 2);
    hr[0] = ab01.x * hr[0] + ab01.y;
    hr[1] = ab01.z * hr[1] + ab01.w;
    hr[2] = ab23.x * hr[2] + ab23.y;
    hr[3] = ab23.z * hr[3] + ab23.w;
  }

  const size_t rbase = ((size_t)(b * S_ + j * CLEN_)) * H_ + h;
  const bf16* gbase = gh + ((size_t)(b * S_ + j * CLEN_)) * N_ + h;
#pragma unroll 4
  for (int t = 0; t < CLEN_; ++t) {
    const bf16x4 gv = *(const bf16x4*)(gbase + (size_t)t * N_);
    const bf16x4 hv = *(const bf16x4*)(gbase + (size_t)t * N_ + H_);
    const float4 rv = *(const float4*)(rin + rbase + (size_t)t * H_);
#pragma unroll
    for (int q = 0; q < 4; ++q) {
      float ca, cb;
      step_coeffs((float)gv[q], (float)hv[q], ca, cb);
      hr[q] = ca * hr[q] + cb;
    }
    const float r0 = hr[0] + rv.x, r1 = hr[1] + rv.y;
    const float r2 = hr[2] + rv.z, r3 = hr[3] + rv.w;
    *(float4*)(rout + rbase + (size_t)t * H_) = make_float4(r0, r1, r2, r3);
    if (gout) {
      bf16x4 o;
      o[0] = (__bf16)r0; o[1] = (__bf16)r1; o[2] = (__bf16)r2; o[3] = (__bf16)r3;
      *(bf16x4*)(gout + rbase + (size_t)t * H_) = o;
    }
  }
  if (j == CHUNKS_ - 1)
    *(float4*)(finals + c) = make_float4(hr[0], hr[1], hr[2], hr[3]);
}

// ---------------------------------------------------------------------------
extern "C" void kernel_launch(void* const* d_in, const int* in_sizes, int n_in,
                              void* d_out, int out_size, void* d_ws,
                              size_t ws_size, hipStream_t stream) {
  const float* x  = (const float*)d_in[0];
  const float* h0 = (const float*)d_in[1];  // (L,B,1,H)
  const float* W0 = (const float*)d_in[2];  // (2H, D)
  const float* b0 = (const float*)d_in[3];  // (2H,)
  const float* Wl = (const float*)d_in[4];  // (L-1, 2H, H)
  const float* bl = (const float*)d_in[5];  // (L-1, 2H)
  float* out    = (float*)d_out;            // (B,S,H) residual stream, in-place
  float* finals = out + (size_t)M_ * H_;    // (L,B,1,H)

  char* ws = (char*)d_ws;
  bf16* gh   = (bf16*)ws;                   // 64 MB: (M_, 2H)
  bf16* bufA = (bf16*)(ws + (64u << 20));   // 32 MB: bf16 A for current layer

  const bool wide = ws_size >= ((size_t)115 << 20);
  bf16*   wb    = wide ? (bf16*)(ws + (96u << 20)) : nullptr;       // 16 MB
  float2* sAB   = (float2*)(ws + ((wide ? 112u : 96u) << 20));      // 2 MB

  // x -> bf16 into bufA (layer-0 A). 16M elems.
  cvt_f32_bf16<<<dim3(M_ * K_ / 8 / 256), 256, 0, stream>>>(x, bufA, (long)M_ * K_);
  if (wide) {  // all weights -> bf16 once: [W0 | Wl] = 4 x (2048x1024)
    cvt_f32_bf16<<<dim3(N_ * K_ / 8 / 256), 256, 0, stream>>>(W0, wb, (long)N_ * K_);
    cvt_f32_bf16<<<dim3(3 * N_ * K_ / 8 / 256), 256, 0, stream>>>(
        Wl, wb + (size_t)N_ * K_, (long)3 * N_ * K_);
  }

  for (int l = 0; l < 4; ++l) {
    const float* Wf = (l == 0) ? W0 : Wl + (size_t)(l - 1) * N_ * K_;
    const float* bi = (l == 0) ? b0 : bl + (size_t)(l - 1) * N_;
    if (wide) {
      gemm256<<<dim3(512), 512, 0, stream>>>(
          bufA, wb + (size_t)l * N_ * K_, bi, gh);
    } else {
      gemm_bias<false><<<dim3(16, 128), 256, 0, stream>>>(
          bufA, nullptr, Wf, bi, gh);
    }
    scan_chunk<<<dim3(8 * CHUNKS_), 256, 0, stream>>>(gh, sAB);
    scan_apply<<<dim3(8 * CHUNKS_), 256, 0, stream>>>(
        gh, sAB, h0 + (size_t)l * B_ * H_, (l == 0) ? x : out, out,
        (l == 3) ? nullptr : bufA, finals + (size_t)l * B_ * H_);
  }
}

// Round 4
// 672.862 us; speedup vs baseline: 1.1023x; 1.1023x over previous
//
#include <hip/hip_runtime.h>
#include <hip/hip_bf16.h>

using bf16 = __hip_bfloat16;
typedef __bf16 bf16x8 __attribute__((ext_vector_type(8)));
typedef __bf16 bf16x4 __attribute__((ext_vector_type(4)));
typedef __bf16 bf16x2 __attribute__((ext_vector_type(2)));
typedef float  f32x4  __attribute__((ext_vector_type(4)));

#define B_ 8
#define S_ 2048
#define H_ 1024
#define M_ (B_ * S_)   // 16384
#define N_ (2 * H_)    // 2048
#define K_ 1024
#define CHUNKS_ 32
#define CLEN_ 64       // 32*64 = 2048 = S_

__device__ __forceinline__ bf16x8 load8f(const float* p) {
  const float4 a = *(const float4*)p;
  const float4 b = *(const float4*)(p + 4);
  bf16x8 r;
  r[0] = (__bf16)a.x; r[1] = (__bf16)a.y; r[2] = (__bf16)a.z; r[3] = (__bf16)a.w;
  r[4] = (__bf16)b.x; r[5] = (__bf16)b.y; r[6] = (__bf16)b.z; r[7] = (__bf16)b.w;
  return r;
}

// f32 -> bf16 bulk convert, 8 elems/thread. n must be multiple of 8.
__global__ __launch_bounds__(256)
void cvt_f32_bf16(const float* __restrict__ src, bf16* __restrict__ dst, long n) {
  const long i = ((long)blockIdx.x * 256 + threadIdx.x) * 8;
  if (i >= n) return;
  *(bf16x8*)(dst + i) = load8f(src + i);
}

// ---------------------------------------------------------------------------
// Fallback GEMM (narrow-workspace path only): m97-style 128x128 tile.
// ---------------------------------------------------------------------------
template <bool WDMA>
__global__ __launch_bounds__(256)
void gemm_bias(const bf16* __restrict__ A, const bf16* __restrict__ Wb,
               const float* __restrict__ Wf, const float* __restrict__ bias,
               bf16* __restrict__ C) {
  __shared__ __align__(16) char lds[16384];
  const int tid  = threadIdx.x;
  const int lane = tid & 63;
  const int wv   = tid >> 6;
  const int wr   = wv >> 1;
  const int wc   = wv & 1;
  const int r15  = lane & 15;
  const int kq   = lane >> 4;
  const int mBase = blockIdx.y * 128;
  const int nBase = blockIdx.x * 128;

  f32x4 acc[4][4];
#pragma unroll
  for (int i = 0; i < 4; ++i)
#pragma unroll
    for (int j = 0; j < 4; ++j)
#pragma unroll
      for (int r = 0; r < 4; ++r) acc[i][j][r] = 0.0f;

  for (int k0 = 0; k0 < K_; k0 += 32) {
    bf16x8 sw[2];
    if constexpr (!WDMA) {
#pragma unroll
      for (int c = 0; c < 2; ++c) {
        const int seg = wv * 2 + c;
        sw[c] = load8f(Wf + (size_t)(nBase + seg * 16 + r15) * K_ + k0 + kq * 8);
      }
    }
    __syncthreads();
#pragma unroll
    for (int c = 0; c < 2; ++c) {
      const int seg = wv * 2 + c;
      const bf16* ga = A + (size_t)(mBase + seg * 16 + r15) * K_ + k0 + kq * 8;
      __builtin_amdgcn_global_load_lds(
          (const __attribute__((address_space(1))) void*)ga,
          (__attribute__((address_space(3))) void*)(lds + seg * 1024), 16, 0, 0);
      if constexpr (WDMA) {
        const bf16* gw = Wb + (size_t)(nBase + seg * 16 + r15) * K_ + k0 + kq * 8;
        __builtin_amdgcn_global_load_lds(
            (const __attribute__((address_space(1))) void*)gw,
            (__attribute__((address_space(3))) void*)(lds + 8192 + seg * 1024), 16, 0, 0);
      } else {
        *(bf16x8*)(lds + 8192 + seg * 1024 + lane * 16) = sw[c];
      }
    }
    __syncthreads();

    bf16x8 af[4], bfr[4];
#pragma unroll
    for (int i = 0; i < 4; ++i)
      af[i] = *(const bf16x8*)(lds + (wr * 4 + i) * 1024 + lane * 16);
#pragma unroll
    for (int j = 0; j < 4; ++j)
      bfr[j] = *(const bf16x8*)(lds + 8192 + (wc * 4 + j) * 1024 + lane * 16);
#pragma unroll
    for (int i = 0; i < 4; ++i)
#pragma unroll
      for (int j = 0; j < 4; ++j)
        acc[i][j] = __builtin_amdgcn_mfma_f32_16x16x32_bf16(af[i], bfr[j],
                                                            acc[i][j], 0, 0, 0);
  }

#pragma unroll
  for (int j = 0; j < 4; ++j) {
    const int col = nBase + wc * 64 + j * 16 + r15;
    const float bv = bias[col];
#pragma unroll
    for (int i = 0; i < 4; ++i) {
      const int row = mBase + wr * 64 + i * 16 + kq * 4;
#pragma unroll
      for (int r = 0; r < 4; ++r)
        C[(size_t)(row + r) * N_ + col] = __float2bfloat16(acc[i][j][r] + bv);
    }
  }
}

// ---------------------------------------------------------------------------
// 256x256 8-phase GEMM (wide path): C[m][n] = sum_k A[m][k]*W[n][k] + bias[n]
// T1 XCD swizzle + T2 XOR-swizzled LDS + T3/T4 8-phase counted-vmcnt + T5.
// (Stable since round 2: ~74.5 us, MfmaUtil 37%, FETCH 49 MB, 0 bank conf.)
//
// Geometry: BM=BN=256, BK=64, 8 waves (2M x 4N), per-wave output 128x64,
// acc = f32x4[8][4]. LDS 128 KiB = 2 buffers x {A[2 halves][128x64 bf16],
// B[2 halves][128x64 bf16]}; half-tile = 16 KiB staged by 2 global_load_lds
// per thread (512 thr x 2 x 16B).
//
// T2 swizzle (involution on 16B chunks within a half-tile, row stride 128B):
//   phys_byte = logical_byte ^ ((row & 7) << 4),  row = logical_byte >> 7.
// Staging keeps LDS dest linear (gload_lds HW constraint) and pre-swizzles
// the per-lane GLOBAL source chunk: src_chunk = t ^ ((t>>3)&7).  Fragment
// ds_read_b128 applies the same XOR => lanes 0-15 (rows 0-15, fixed col)
// land on distinct bank-quads, 2-way (free) instead of 16-way.
//
// Phase ledger per iteration (tiles t in buf0 = phases P1-4, t+1 in buf1 =
// P5-8; one half-tile stage per phase; slot is free only after the last
// phase that ds_reads it -- B halves after P2, A halves after P3):
//   P1: ds A0-3,B0-1 (12) stage t+1.A1   P5: ds A0-3,B0-1  stage t+2.A1
//   P2: ds B2-3      (4)  stage t+1.B1   P6: ds B2-3       stage t+2.B1
//   P3: ds A4-7      (8)  stage t+2.B0   P7: ds A4-7       stage t+3.B0
//   P4: --                stage t+2.A0   P8: --            stage t+3.A0
//   vmcnt(4) at end of P4/P8: 6 stages (12 loads) in flight, oldest 4 stages
//   (= next tile complete) must land, newest 2 (4 loads) may remain.
// ---------------------------------------------------------------------------
#define BK_    64
#define NT_    (K_ / BK_)   // 16
#define LBUF_  65536
#define LBOFF_ 32768
#define LHALF_ 16384

__global__ __launch_bounds__(512, 2)
void gemm256(const bf16* __restrict__ A, const bf16* __restrict__ W,
             const float* __restrict__ bias, bf16* __restrict__ C) {
  __shared__ __align__(16) char lds[131072];
  const int tid  = threadIdx.x;
  const int lane = tid & 63;
  const int wv   = tid >> 6;   // 0..7
  const int wm   = wv >> 2;    // 0..1  (row half)
  const int wn   = wv & 3;     // 0..3  (64-col strip)
  const int r15  = lane & 15;
  const int kq   = lane >> 4;

  // T1: bijective XCD swizzle. nwg=512, 512%8==0. XCD x = flat%8 gets
  // sw in [x*64, x*64+64) -> row panels [8x,8x+8) x all 8 col tiles:
  // A panels become XCD-local in L2.
  const int flat = blockIdx.x;
  const int sw   = (flat & 7) * 64 + (flat >> 3);
  const int by   = sw >> 3;    // 0..63
  const int bx   = sw & 7;     // 0..7
  const int mBase = by * 256;
  const int nBase = bx * 256;

  // staging: per-thread loop-invariant source/dest offsets
  size_t srcOff[2];
  int dstOff[2];
#pragma unroll
  for (int q = 0; q < 2; ++q) {
    const int t  = q * 512 + tid;                 // 16B chunk id 0..1023
    const int cc = (t & 7) ^ ((t >> 3) & 7);      // pre-swizzled col chunk
    srcOff[q] = (size_t)(t >> 3) * K_ + cc * 8;   // elements
    dstOff[q] = q * 8192 + wv * 1024;             // linear LDS bytes (wave-uniform)
  }
  const bf16* aH[2] = {A + (size_t)mBase * K_, A + (size_t)(mBase + 128) * K_};
  const bf16* wH[2] = {W + (size_t)nBase * K_, W + (size_t)(nBase + 128) * K_};

#define STAGE(GB, LOFF)                                                        \
  { _Pragma("unroll") for (int q_ = 0; q_ < 2; ++q_)                           \
      __builtin_amdgcn_global_load_lds(                                        \
          (const __attribute__((address_space(1))) void*)((GB) + srcOff[q_]),  \
          (__attribute__((address_space(3))) void*)(lds + (LOFF) + dstOff[q_]),\
          16, 0, 0); }

  // fragment read offsets (T2 read-side XOR; row&7 == r15&7)
  const int xsw  = (r15 & 7) << 4;
  const int col0 = (kq * 16) ^ xsw;
  const int col1 = (64 + kq * 16) ^ xsw;
  const int aRow = wm * LHALF_ + r15 * 128;
  const int bRow = LBOFF_ + (wn >> 1) * LHALF_ + ((wn & 1) * 64 + r15) * 128;

  f32x4 acc[8][4];
#pragma unroll
  for (int i = 0; i < 8; ++i)
#pragma unroll
    for (int j = 0; j < 4; ++j)
#pragma unroll
      for (int r = 0; r < 4; ++r) acc[i][j][r] = 0.0f;

  bf16x8 aF[4][2], bF[4][2];

#define LD_A(BO)                                                               \
  { _Pragma("unroll") for (int i_ = 0; i_ < 4; ++i_) {                         \
      aF[i_][0] = *(const bf16x8*)(lds + (BO) + i_ * 2048 + col0);             \
      aF[i_][1] = *(const bf16x8*)(lds + (BO) + i_ * 2048 + col1); } }
  // BO carries aRow (+ 8192 for rows 64..127)

#define LD_B(J0, BO)                                                           \
  { _Pragma("unroll") for (int j_ = 0; j_ < 2; ++j_) {                         \
      bF[(J0) + j_][0] =                                                       \
          *(const bf16x8*)(lds + (BO) + bRow + ((J0) + j_) * 2048 + col0);     \
      bF[(J0) + j_][1] =                                                       \
          *(const bf16x8*)(lds + (BO) + bRow + ((J0) + j_) * 2048 + col1); } }

#define MFMA_Q(I0, J0)                                                         \
  { _Pragma("unroll") for (int i_ = 0; i_ < 4; ++i_)                           \
    _Pragma("unroll") for (int j_ = 0; j_ < 2; ++j_)                           \
    _Pragma("unroll") for (int k_ = 0; k_ < 2; ++k_)                           \
      acc[(I0) + i_][(J0) + j_] = __builtin_amdgcn_mfma_f32_16x16x32_bf16(     \
          aF[i_][k_], bF[(J0) + j_][k_], acc[(I0) + i_][(J0) + j_], 0, 0, 0); }

#define PH_BAR()                                                               \
  __builtin_amdgcn_sched_barrier(0);                                           \
  __builtin_amdgcn_s_barrier();                                                \
  asm volatile("s_waitcnt lgkmcnt(0)" ::: "memory");                           \
  __builtin_amdgcn_sched_barrier(0);                                           \
  __builtin_amdgcn_s_setprio(1);

#define PH_END()                                                               \
  __builtin_amdgcn_s_setprio(0);                                               \
  __builtin_amdgcn_sched_barrier(0);                                           \
  __builtin_amdgcn_s_barrier();

#define PH_END_VM(N)                                                           \
  __builtin_amdgcn_s_setprio(0);                                               \
  __builtin_amdgcn_sched_barrier(0);                                           \
  asm volatile("s_waitcnt vmcnt(" #N ")" ::: "memory");                        \
  __builtin_amdgcn_s_barrier();

  // Prologue: tile0 complete + t1.{B0,A0} in flight (matches steady state).
  STAGE(aH[0], 0);
  STAGE(aH[1], LHALF_);
  STAGE(wH[0], LBOFF_);
  STAGE(wH[1], LBOFF_ + LHALF_);
  STAGE(wH[0] + BK_, LBUF_ + LBOFF_);
  STAGE(aH[0] + BK_, LBUF_);
  asm volatile("s_waitcnt vmcnt(4)" ::: "memory");
  __builtin_amdgcn_s_barrier();

#pragma unroll 1
  for (int t = 0; t < NT_ - 2; t += 2) {
    const int o1 = (t + 1) * BK_, o2 = (t + 2) * BK_, o3 = (t + 3) * BK_;
    // ---- tile t (buf0) ----
    LD_A(aRow); LD_B(0, 0);
    STAGE(aH[1] + o1, LBUF_ + LHALF_);             // t+1.A1
    asm volatile("s_waitcnt lgkmcnt(8)" ::: "memory");
    PH_BAR(); MFMA_Q(0, 0); PH_END();
    LD_B(2, 0);
    STAGE(wH[1] + o1, LBUF_ + LBOFF_ + LHALF_);    // t+1.B1
    PH_BAR(); MFMA_Q(0, 2); PH_END();
    LD_A(aRow + 8192);
    STAGE(wH[0] + o2, LBOFF_);                     // t+2.B0 (buf0.B0 free after P2)
    PH_BAR(); MFMA_Q(4, 0); PH_END();
    STAGE(aH[0] + o2, 0);                          // t+2.A0 (buf0.A0 free after P3)
    PH_BAR(); MFMA_Q(4, 2); PH_END_VM(4);          // t+1 landed, 4 loads in flight
    // ---- tile t+1 (buf1) ----
    LD_A(LBUF_ + aRow); LD_B(0, LBUF_);
    STAGE(aH[1] + o2, LHALF_);                     // t+2.A1
    asm volatile("s_waitcnt lgkmcnt(8)" ::: "memory");
    PH_BAR(); MFMA_Q(0, 0); PH_END();
    LD_B(2, LBUF_);
    STAGE(wH[1] + o2, LBOFF_ + LHALF_);            // t+2.B1
    PH_BAR(); MFMA_Q(0, 2); PH_END();
    LD_A(LBUF_ + aRow + 8192);
    STAGE(wH[0] + o3, LBUF_ + LBOFF_);             // t+3.B0
    PH_BAR(); MFMA_Q(4, 0); PH_END();
    STAGE(aH[0] + o3, LBUF_);                      // t+3.A0
    PH_BAR(); MFMA_Q(4, 2); PH_END_VM(4);          // t+2 landed
  }

  // Tail: tiles 14 (buf0) and 15 (buf1); only t15.{A1,B1} left to stage.
  {
    const int o1 = (NT_ - 1) * BK_;
    LD_A(aRow); LD_B(0, 0);
    STAGE(aH[1] + o1, LBUF_ + LHALF_);             // t15.A1
    asm volatile("s_waitcnt lgkmcnt(8)" ::: "memory");
    PH_BAR(); MFMA_Q(0, 0); PH_END();
    LD_B(2, 0);
    STAGE(wH[1] + o1, LBUF_ + LBOFF_ + LHALF_);    // t15.B1
    PH_BAR(); MFMA_Q(0, 2); PH_END();
    LD_A(aRow + 8192);
    PH_BAR(); MFMA_Q(4, 0); PH_END();
    PH_BAR(); MFMA_Q(4, 2); PH_END_VM(0);          // t15 fully landed
    // tile 15, no stages
    LD_A(LBUF_ + aRow); LD_B(0, LBUF_);
    PH_BAR(); MFMA_Q(0, 0); PH_END();
    LD_B(2, LBUF_);
    PH_BAR(); MFMA_Q(0, 2); PH_END();
    LD_A(LBUF_ + aRow + 8192);
    PH_BAR(); MFMA_Q(4, 0); PH_END();
    PH_BAR(); MFMA_Q(4, 2);
    __builtin_amdgcn_s_setprio(0);
  }

  // Epilogue. C/D layout: col = lane&15, row = (lane>>4)*4 + r (r3-verified).
#pragma unroll
  for (int j = 0; j < 4; ++j) {
    const int col = nBase + wn * 64 + j * 16 + r15;
    const float bv = bias[col];
#pragma unroll
    for (int i = 0; i < 8; ++i) {
      const int row0 = mBase + wm * 128 + i * 16 + kq * 4;
#pragma unroll
      for (int r = 0; r < 4; ++r)
        C[(size_t)(row0 + r) * N_ + col] = __float2bfloat16(acc[i][j][r] + bv);
    }
  }
#undef STAGE
#undef LD_A
#undef LD_B
#undef MFMA_Q
#undef PH_BAR
#undef PH_END
#undef PH_END_VM
}

// ---------------------------------------------------------------------------
// Scan pointwise math:  h_t = ca*h_{t-1} + cb
//   ca = 1 - z = 1/(1+exp(gate));  cb = z * g(hidden)
//   g(x) = x + 0.5 (x>=0) else sigmoid(x)
// ---------------------------------------------------------------------------
__device__ __forceinline__ float rcpf(float x) { return __builtin_amdgcn_rcpf(x); }

__device__ __forceinline__ void step_coeffs(float gate, float hidden,
                                            float& ca, float& cb) {
  const float e1 = __expf(gate);
  ca = rcpf(1.0f + e1);
  const float z = 1.0f - ca;
  float g;
  if (hidden >= 0.0f) {
    g = hidden + 0.5f;
  } else {
    const float e2 = __expf(hidden);
    g = e2 * rcpf(1.0f + e2);
  }
  cb = z * g;
}

__device__ __forceinline__ float g_of(float x) {
  if (x >= 0.0f) return x + 0.5f;
  const float e = __expf(x);
  return e * rcpf(1.0f + e);
}

// Phase A: per (channel, chunk) composed affine (A,B): h_out = A*h_in + B.
// 2 channels/thread, 512 blocks (2 channel-halves x 8 batch x 32 chunks)
// -> 8 waves/CU. Loads only; compiler pipelines freely (all __restrict__).
__global__ __launch_bounds__(256)
void scan_chunk(const bf16* __restrict__ gh, float2* __restrict__ sAB) {
  const int tx = threadIdx.x, bx = blockIdx.x;
  const int half = bx & 1, b = (bx >> 1) & 7, j = bx >> 4;
  const int h = half * 512 + tx * 2;
  const int c = b * 1024 + h;
  const bf16* gbase = gh + ((size_t)(b * S_ + j * CLEN_)) * N_ + h;
  float A0 = 1.0f, B0 = 0.0f, A1 = 1.0f, B1 = 0.0f;
#pragma unroll 8
  for (int t = 0; t < CLEN_; ++t) {
    const bf16x2 gv = *(const bf16x2*)(gbase + (size_t)t * N_);
    const bf16x2 hv = *(const bf16x2*)(gbase + (size_t)t * N_ + H_);
    float ca, cb;
    step_coeffs((float)gv[0], (float)hv[0], ca, cb);
    A0 *= ca;  B0 = ca * B0 + cb;
    step_coeffs((float)gv[1], (float)hv[1], ca, cb);
    A1 *= ca;  B1 = ca * B1 + cb;
  }
  *(float4*)(sAB + (size_t)j * (B_ * H_) + c) = make_float4(A0, B0, A1, B1);
}

// Phase B+C fused: each block recomputes its chunk's carry by walking the
// sAB prefix [0, j) for its 2 channels, then applies the chunk.
//
// ALIASING NOTE: rin may equal rout (in-place residual for l>=1), so they are
// deliberately NOT __restrict__. To stop that from serializing the t-loop
// (store[t] blocking load[t+1] hoisting), the loop is hand-pipelined in
// groups of 8: all 24 loads of a group issue before any compute/store of the
// group. Within a group element t's load precedes its own store and all
// addresses across t are distinct, so this is exact-aliasing-safe.
__global__ __launch_bounds__(256)
void scan_apply(const bf16* __restrict__ gh, const float2* __restrict__ sAB,
                const float* __restrict__ hprev,
                const float* rin, float* rout, bf16* __restrict__ gout,
                float* __restrict__ finals) {
  const int tx = threadIdx.x, bx = blockIdx.x;
  const int half = bx & 1, b = (bx >> 1) & 7, j = bx >> 4;
  const int h = half * 512 + tx * 2;
  const int c = b * 1024 + h;

  float h0, h1;
  {
    const float2 hp = *(const float2*)(hprev + c);
    h0 = g_of(hp.x); h1 = g_of(hp.y);
  }
  for (int jj = 0; jj < j; ++jj) {
    const float4 ab = *(const float4*)(sAB + (size_t)jj * (B_ * H_) + c);
    h0 = ab.x * h0 + ab.y;
    h1 = ab.z * h1 + ab.w;
  }

  const size_t rbase = ((size_t)(b * S_ + j * CLEN_)) * H_ + h;
  const bf16* gbase = gh + ((size_t)(b * S_ + j * CLEN_)) * N_ + h;
#pragma unroll 1
  for (int tt = 0; tt < CLEN_; tt += 8) {
    bf16x2 gv[8], hv[8];
    float2 rv[8];
#pragma unroll
    for (int u = 0; u < 8; ++u) {
      const size_t t = (size_t)(tt + u);
      gv[u] = *(const bf16x2*)(gbase + t * N_);
      hv[u] = *(const bf16x2*)(gbase + t * N_ + H_);
      rv[u] = *(const float2*)(rin + rbase + t * H_);
    }
#pragma unroll
    for (int u = 0; u < 8; ++u) {
      const size_t t = (size_t)(tt + u);
      float ca, cb;
      step_coeffs((float)gv[u][0], (float)hv[u][0], ca, cb);
      h0 = ca * h0 + cb;
      step_coeffs((float)gv[u][1], (float)hv[u][1], ca, cb);
      h1 = ca * h1 + cb;
      const float r0 = h0 + rv[u].x;
      const float r1 = h1 + rv[u].y;
      *(float2*)(rout + rbase + t * H_) = make_float2(r0, r1);
      if (gout) {
        bf16x2 o;
        o[0] = (__bf16)r0; o[1] = (__bf16)r1;
        *(bf16x2*)(gout + rbase + t * H_) = o;
      }
    }
  }
  if (j == CHUNKS_ - 1)
    *(float2*)(finals + c) = make_float2(h0, h1);
}

// ---------------------------------------------------------------------------
extern "C" void kernel_launch(void* const* d_in, const int* in_sizes, int n_in,
                              void* d_out, int out_size, void* d_ws,
                              size_t ws_size, hipStream_t stream) {
  const float* x  = (const float*)d_in[0];
  const float* h0 = (const float*)d_in[1];  // (L,B,1,H)
  const float* W0 = (const float*)d_in[2];  // (2H, D)
  const float* b0 = (const float*)d_in[3];  // (2H,)
  const float* Wl = (const float*)d_in[4];  // (L-1, 2H, H)
  const float* bl = (const float*)d_in[5];  // (L-1, 2H)
  float* out    = (float*)d_out;            // (B,S,H) residual stream, in-place
  float* finals = out + (size_t)M_ * H_;    // (L,B,1,H)

  char* ws = (char*)d_ws;
  bf16* gh   = (bf16*)ws;                   // 64 MB: (M_, 2H)
  bf16* bufA = (bf16*)(ws + (64u << 20));   // 32 MB: bf16 A for current layer

  const bool wide = ws_size >= ((size_t)115 << 20);
  bf16*   wb    = wide ? (bf16*)(ws + (96u << 20)) : nullptr;       // 16 MB
  float2* sAB   = (float2*)(ws + ((wide ? 112u : 96u) << 20));      // 2 MB

  // x -> bf16 into bufA (layer-0 A). 16M elems.
  cvt_f32_bf16<<<dim3(M_ * K_ / 8 / 256), 256, 0, stream>>>(x, bufA, (long)M_ * K_);
  if (wide) {  // all weights -> bf16 once: [W0 | Wl] = 4 x (2048x1024)
    cvt_f32_bf16<<<dim3(N_ * K_ / 8 / 256), 256, 0, stream>>>(W0, wb, (long)N_ * K_);
    cvt_f32_bf16<<<dim3(3 * N_ * K_ / 8 / 256), 256, 0, stream>>>(
        Wl, wb + (size_t)N_ * K_, (long)3 * N_ * K_);
  }

  for (int l = 0; l < 4; ++l) {
    const float* Wf = (l == 0) ? W0 : Wl + (size_t)(l - 1) * N_ * K_;
    const float* bi = (l == 0) ? b0 : bl + (size_t)(l - 1) * N_;
    if (wide) {
      gemm256<<<dim3(512), 512, 0, stream>>>(
          bufA, wb + (size_t)l * N_ * K_, bi, gh);
    } else {
      gemm_bias<false><<<dim3(16, 128), 256, 0, stream>>>(
          bufA, nullptr, Wf, bi, gh);
    }
    scan_chunk<<<dim3(512), 256, 0, stream>>>(gh, sAB);
    scan_apply<<<dim3(512), 256, 0, stream>>>(
        gh, sAB, h0 + (size_t)l * B_ * H_, (l == 0) ? x : out, out,
        (l == 3) ? nullptr : bufA, finals + (size_t)l * B_ * H_);
  }
}

// Round 6
// 565.928 us; speedup vs baseline: 1.3106x; 1.1890x over previous
//
#include <hip/hip_runtime.h>
#include <hip/hip_bf16.h>

using bf16 = __hip_bfloat16;
typedef __bf16 bf16x8 __attribute__((ext_vector_type(8)));
typedef __bf16 bf16x4 __attribute__((ext_vector_type(4)));
typedef __bf16 bf16x2 __attribute__((ext_vector_type(2)));
typedef float  f32x4  __attribute__((ext_vector_type(4)));

#define B_ 8
#define S_ 2048
#define H_ 1024
#define M_ (B_ * S_)   // 16384
#define N_ (2 * H_)    // 2048
#define K_ 1024
#define CHUNKS_ 32
#define CLEN_ 64       // 32*64 = 2048 = S_

__device__ __forceinline__ bf16x8 load8f(const float* p) {
  const float4 a = *(const float4*)p;
  const float4 b = *(const float4*)(p + 4);
  bf16x8 r;
  r[0] = (__bf16)a.x; r[1] = (__bf16)a.y; r[2] = (__bf16)a.z; r[3] = (__bf16)a.w;
  r[4] = (__bf16)b.x; r[5] = (__bf16)b.y; r[6] = (__bf16)b.z; r[7] = (__bf16)b.w;
  return r;
}

// f32 -> bf16 bulk convert, 8 elems/thread. n must be multiple of 8.
__global__ __launch_bounds__(256)
void cvt_f32_bf16(const float* __restrict__ src, bf16* __restrict__ dst, long n) {
  const long i = ((long)blockIdx.x * 256 + threadIdx.x) * 8;
  if (i >= n) return;
  *(bf16x8*)(dst + i) = load8f(src + i);
}

// ---------------------------------------------------------------------------
// W pack+convert: nmat matrices of (2H x K) f32 -> bf16 with row permutation
// so that channel c's gate/hidden rows become adjacent 16-col groups in C:
//   packed row 32g+u      = gate  channel 16g+u   (orig row 16g+u)
//   packed row 32g+16+u   = hidden channel 16g+u  (orig row H_+16g+u)
// => C cols [32g..32g+15] = gate of ch [16g..16g+15], [32g+16..] = hidden.
// ---------------------------------------------------------------------------
__global__ __launch_bounds__(256)
void cvt_pack_w(const float* __restrict__ src, bf16* __restrict__ dst, int nmat) {
  const long idx = (long)blockIdx.x * 256 + threadIdx.x;
  const long e = idx * 8;
  if (e >= (long)nmat * N_ * K_) return;
  const int m = (int)(e / ((long)N_ * K_));
  const long em = e - (long)m * N_ * K_;
  const int prow = (int)(em >> 10);          // packed row 0..2047 (K_=1024)
  const int col  = (int)(em & (K_ - 1));
  const int g = prow >> 5, ty = (prow >> 4) & 1, u = prow & 15;
  const int orow = ty * H_ + g * 16 + u;
  *(bf16x8*)(dst + ((long)m * N_ + prow) * K_ + col) =
      load8f(src + ((long)m * N_ + orow) * K_ + col);
}

// ---------------------------------------------------------------------------
// Scan pointwise math:  h_t = ca*h_{t-1} + cb
//   ca = 1 - z = 1/(1+exp(gate));  cb = z * g(hidden)
//   g(x) = x + 0.5 (x>=0) else sigmoid(x)
// ---------------------------------------------------------------------------
__device__ __forceinline__ float rcpf(float x) { return __builtin_amdgcn_rcpf(x); }

__device__ __forceinline__ void step_coeffs(float gate, float hidden,
                                            float& ca, float& cb) {
  const float e1 = __expf(gate);
  ca = rcpf(1.0f + e1);
  const float z = 1.0f - ca;
  float g;
  if (hidden >= 0.0f) {
    g = hidden + 0.5f;
  } else {
    const float e2 = __expf(hidden);
    g = e2 * rcpf(1.0f + e2);
  }
  cb = z * g;
}

__device__ __forceinline__ float g_of(float x) {
  if (x >= 0.0f) return x + 0.5f;
  const float e = __expf(x);
  return e * rcpf(1.0f + e);
}

// ---------------------------------------------------------------------------
// 256x256 8-phase GEMM + fused minGRU coefficient epilogue.
// K-loop identical to round 2-4 (stable ~75-86 us, MfmaUtil 33-37%, 0 bank
// conflicts). Epilogue:
//   - W is row-packed (cvt_pack_w) so lane r15 of col-strip wn holds
//     (gate,hidden) of channels x0=(nBase+wn*64)/2+r15 and x1=x0+16 in
//     acc[i][0/1] and acc[i][2/3].
//   - computes ca,cb in f32 (full-precision gemm + bias), rounds to bf16,
//     stores into C (gate slot <- ca, hidden slot <- cb).
//   - composes per-chunk affine (A,B) from the bf16-ROUNDED ca,cb (keeps
//     sAB consistent with what scan_apply reads): r-runs in-lane, ordered
//     cross-kq compose via 2 shfl_xor butterflies, i-segments in-lane;
//     kq==0 lanes write sAB. This deletes the scan_chunk kernel.
//
// Phase ledger / T1 / T2 / T4 / T5: see round-2 comments (unchanged).
// ---------------------------------------------------------------------------
#define BK_    64
#define NT_    (K_ / BK_)   // 16
#define LBUF_  65536
#define LBOFF_ 32768
#define LHALF_ 16384

__global__ __launch_bounds__(512, 2)
void gemm256(const bf16* __restrict__ A, const bf16* __restrict__ W,
             const float* __restrict__ bias, bf16* __restrict__ C,
             float2* __restrict__ sAB) {
  __shared__ __align__(16) char lds[131072];
  const int tid  = threadIdx.x;
  const int lane = tid & 63;
  const int wv   = tid >> 6;   // 0..7
  const int wm   = wv >> 2;    // 0..1  (row half)
  const int wn   = wv & 3;     // 0..3  (64-col strip)
  const int r15  = lane & 15;
  const int kq   = lane >> 4;

  // T1: bijective XCD swizzle (512 blocks, 512%8==0).
  const int flat = blockIdx.x;
  const int sw   = (flat & 7) * 64 + (flat >> 3);
  const int by   = sw >> 3;    // 0..63
  const int bx   = sw & 7;     // 0..7
  const int mBase = by * 256;
  const int nBase = bx * 256;

  size_t srcOff[2];
  int dstOff[2];
#pragma unroll
  for (int q = 0; q < 2; ++q) {
    const int t  = q * 512 + tid;                 // 16B chunk id 0..1023
    const int cc = (t & 7) ^ ((t >> 3) & 7);      // pre-swizzled col chunk
    srcOff[q] = (size_t)(t >> 3) * K_ + cc * 8;
    dstOff[q] = q * 8192 + wv * 1024;
  }
  const bf16* aH[2] = {A + (size_t)mBase * K_, A + (size_t)(mBase + 128) * K_};
  const bf16* wH[2] = {W + (size_t)nBase * K_, W + (size_t)(nBase + 128) * K_};

#define STAGE(GB, LOFF)                                                        \
  { _Pragma("unroll") for (int q_ = 0; q_ < 2; ++q_)                           \
      __builtin_amdgcn_global_load_lds(                                        \
          (const __attribute__((address_space(1))) void*)((GB) + srcOff[q_]),  \
          (__attribute__((address_space(3))) void*)(lds + (LOFF) + dstOff[q_]),\
          16, 0, 0); }

  const int xsw  = (r15 & 7) << 4;
  const int col0 = (kq * 16) ^ xsw;
  const int col1 = (64 + kq * 16) ^ xsw;
  const int aRow = wm * LHALF_ + r15 * 128;
  const int bRow = LBOFF_ + (wn >> 1) * LHALF_ + ((wn & 1) * 64 + r15) * 128;

  f32x4 acc[8][4];
#pragma unroll
  for (int i = 0; i < 8; ++i)
#pragma unroll
    for (int j = 0; j < 4; ++j)
#pragma unroll
      for (int r = 0; r < 4; ++r) acc[i][j][r] = 0.0f;

  bf16x8 aF[4][2], bF[4][2];

#define LD_A(BO)                                                               \
  { _Pragma("unroll") for (int i_ = 0; i_ < 4; ++i_) {                         \
      aF[i_][0] = *(const bf16x8*)(lds + (BO) + i_ * 2048 + col0);             \
      aF[i_][1] = *(const bf16x8*)(lds + (BO) + i_ * 2048 + col1); } }

#define LD_B(J0, BO)                                                           \
  { _Pragma("unroll") for (int j_ = 0; j_ < 2; ++j_) {                         \
      bF[(J0) + j_][0] =                                                       \
          *(const bf16x8*)(lds + (BO) + bRow + ((J0) + j_) * 2048 + col0);     \
      bF[(J0) + j_][1] =                                                       \
          *(const bf16x8*)(lds + (BO) + bRow + ((J0) + j_) * 2048 + col1); } }

#define MFMA_Q(I0, J0)                                                         \
  { _Pragma("unroll") for (int i_ = 0; i_ < 4; ++i_)                           \
    _Pragma("unroll") for (int j_ = 0; j_ < 2; ++j_)                           \
    _Pragma("unroll") for (int k_ = 0; k_ < 2; ++k_)                           \
      acc[(I0) + i_][(J0) + j_] = __builtin_amdgcn_mfma_f32_16x16x32_bf16(     \
          aF[i_][k_], bF[(J0) + j_][k_], acc[(I0) + i_][(J0) + j_], 0, 0, 0); }

#define PH_BAR()                                                               \
  __builtin_amdgcn_sched_barrier(0);                                           \
  __builtin_amdgcn_s_barrier();                                                \
  asm volatile("s_waitcnt lgkmcnt(0)" ::: "memory");                           \
  __builtin_amdgcn_sched_barrier(0);                                           \
  __builtin_amdgcn_s_setprio(1);

#define PH_END()                                                               \
  __builtin_amdgcn_s_setprio(0);                                               \
  __builtin_amdgcn_sched_barrier(0);                                           \
  __builtin_amdgcn_s_barrier();

#define PH_END_VM(N)                                                           \
  __builtin_amdgcn_s_setprio(0);                                               \
  __builtin_amdgcn_sched_barrier(0);                                           \
  asm volatile("s_waitcnt vmcnt(" #N ")" ::: "memory");                        \
  __builtin_amdgcn_s_barrier();

  // Prologue: tile0 complete + t1.{B0,A0} in flight.
  STAGE(aH[0], 0);
  STAGE(aH[1], LHALF_);
  STAGE(wH[0], LBOFF_);
  STAGE(wH[1], LBOFF_ + LHALF_);
  STAGE(wH[0] + BK_, LBUF_ + LBOFF_);
  STAGE(aH[0] + BK_, LBUF_);
  asm volatile("s_waitcnt vmcnt(4)" ::: "memory");
  __builtin_amdgcn_s_barrier();

#pragma unroll 1
  for (int t = 0; t < NT_ - 2; t += 2) {
    const int o1 = (t + 1) * BK_, o2 = (t + 2) * BK_, o3 = (t + 3) * BK_;
    // ---- tile t (buf0) ----
    LD_A(aRow); LD_B(0, 0);
    STAGE(aH[1] + o1, LBUF_ + LHALF_);             // t+1.A1
    asm volatile("s_waitcnt lgkmcnt(8)" ::: "memory");
    PH_BAR(); MFMA_Q(0, 0); PH_END();
    LD_B(2, 0);
    STAGE(wH[1] + o1, LBUF_ + LBOFF_ + LHALF_);    // t+1.B1
    PH_BAR(); MFMA_Q(0, 2); PH_END();
    LD_A(aRow + 8192);
    STAGE(wH[0] + o2, LBOFF_);                     // t+2.B0
    PH_BAR(); MFMA_Q(4, 0); PH_END();
    STAGE(aH[0] + o2, 0);                          // t+2.A0
    PH_BAR(); MFMA_Q(4, 2); PH_END_VM(4);          // t+1 landed
    // ---- tile t+1 (buf1) ----
    LD_A(LBUF_ + aRow); LD_B(0, LBUF_);
    STAGE(aH[1] + o2, LHALF_);                     // t+2.A1
    asm volatile("s_waitcnt lgkmcnt(8)" ::: "memory");
    PH_BAR(); MFMA_Q(0, 0); PH_END();
    LD_B(2, LBUF_);
    STAGE(wH[1] + o2, LBOFF_ + LHALF_);            // t+2.B1
    PH_BAR(); MFMA_Q(0, 2); PH_END();
    LD_A(LBUF_ + aRow + 8192);
    STAGE(wH[0] + o3, LBUF_ + LBOFF_);             // t+3.B0
    PH_BAR(); MFMA_Q(4, 0); PH_END();
    STAGE(aH[0] + o3, LBUF_);                      // t+3.A0
    PH_BAR(); MFMA_Q(4, 2); PH_END_VM(4);          // t+2 landed
  }

  // Tail: tiles 14 (buf0) and 15 (buf1).
  {
    const int o1 = (NT_ - 1) * BK_;
    LD_A(aRow); LD_B(0, 0);
    STAGE(aH[1] + o1, LBUF_ + LHALF_);             // t15.A1
    asm volatile("s_waitcnt lgkmcnt(8)" ::: "memory");
    PH_BAR(); MFMA_Q(0, 0); PH_END();
    LD_B(2, 0);
    STAGE(wH[1] + o1, LBUF_ + LBOFF_ + LHALF_);    // t15.B1
    PH_BAR(); MFMA_Q(0, 2); PH_END();
    LD_A(aRow + 8192);
    PH_BAR(); MFMA_Q(4, 0); PH_END();
    PH_BAR(); MFMA_Q(4, 2); PH_END_VM(0);          // t15 fully landed
    LD_A(LBUF_ + aRow); LD_B(0, LBUF_);
    PH_BAR(); MFMA_Q(0, 0); PH_END();
    LD_B(2, LBUF_);
    PH_BAR(); MFMA_Q(0, 2); PH_END();
    LD_A(LBUF_ + aRow + 8192);
    PH_BAR(); MFMA_Q(4, 0); PH_END();
    PH_BAR(); MFMA_Q(4, 2);
    __builtin_amdgcn_s_setprio(0);
  }

  // ---------------- fused epilogue ----------------
  // C/D layout: col = lane&15 (+16*jj), row = wm*128 + i*16 + kq*4 + r.
  const int colBase = nBase + wn * 64;      // multiple of 64
  const int x0 = (colBase >> 1) + r15;      // channel for jj pair 0/1
  const int x1 = x0 + 16;                   // channel for jj pair 2/3
  const float bg0 = bias[x0], bh0 = bias[H_ + x0];
  const float bg1 = bias[x1], bh1 = bias[H_ + x1];

  // per (channel, i): affine of the lane's 4-row run (rows i*16+kq*4+r)
  float segA[2][8], segB[2][8];
#pragma unroll
  for (int i = 0; i < 8; ++i) {
    float A0 = 1.f, B0 = 0.f, A1 = 1.f, B1 = 0.f;
    const size_t rw0 = (size_t)(mBase + wm * 128 + i * 16 + kq * 4) * N_;
#pragma unroll
    for (int r = 0; r < 4; ++r) {
      float ca0, cb0, ca1, cb1;
      step_coeffs(acc[i][0][r] + bg0, acc[i][1][r] + bh0, ca0, cb0);
      step_coeffs(acc[i][2][r] + bg1, acc[i][3][r] + bh1, ca1, cb1);
      const bf16 qa0 = __float2bfloat16(ca0), qb0 = __float2bfloat16(cb0);
      const bf16 qa1 = __float2bfloat16(ca1), qb1 = __float2bfloat16(cb1);
      const size_t rw = rw0 + (size_t)r * N_;
      C[rw + colBase + r15]      = qa0;   // gate slot  <- ca  (ch x0)
      C[rw + colBase + 16 + r15] = qb0;   // hidden slot<- cb  (ch x0)
      C[rw + colBase + 32 + r15] = qa1;   // ch x1
      C[rw + colBase + 48 + r15] = qb1;
      // compose with ROUNDED values (consistent with what apply reads)
      const float fa0 = __bfloat162float(qa0), fb0 = __bfloat162float(qb0);
      const float fa1 = __bfloat162float(qa1), fb1 = __bfloat162float(qb1);
      A0 = fa0 * A0; B0 = fa0 * B0 + fb0;
      A1 = fa1 * A1; B1 = fa1 * B1 + fb1;
    }
    segA[0][i] = A0; segB[0][i] = B0;
    segA[1][i] = A1; segB[1][i] = B1;
  }

  // ordered cross-kq compose: rows within i are kq-major (i*16 + kq*4 + r).
  // stage1 pairs kq {0,1},{2,3} (lane bit 4); stage2 pairs {01},{23} (bit 5).
  // result = high ∘ low: A = Ah*Al, B = Ah*Bl + Bh.
#pragma unroll
  for (int ch = 0; ch < 2; ++ch)
#pragma unroll
    for (int i = 0; i < 8; ++i) {
      float A = segA[ch][i], Bv = segB[ch][i];
      {
        const float pA = __shfl_xor(A, 16, 64);
        const float pB = __shfl_xor(Bv, 16, 64);
        Bv = (lane & 16) ? (A * pB + Bv) : (pA * Bv + pB);
        A = A * pA;
      }
      {
        const float pA = __shfl_xor(A, 32, 64);
        const float pB = __shfl_xor(Bv, 32, 64);
        Bv = (lane & 32) ? (A * pB + Bv) : (pA * Bv + pB);
        A = A * pA;
      }
      segA[ch][i] = A; segB[ch][i] = Bv;
    }

  // per-chunk compose over i (chunk c: i in [4c,4c+4)) and write sAB.
  if (kq == 0) {
    const int b_idx = mBase / S_;                       // batch
    const int j0 = ((mBase % S_) + wm * 128) / 64;      // first chunk idx
#pragma unroll
    for (int c = 0; c < 2; ++c) {
#pragma unroll
      for (int ch = 0; ch < 2; ++ch) {
        float A = 1.f, Bv = 0.f;
#pragma unroll
        for (int i = 4 * c; i < 4 * c + 4; ++i) {
          A = segA[ch][i] * A;
          Bv = segA[ch][i] * Bv + segB[ch][i];
        }
        const int x = (ch == 0) ? x0 : x1;
        sAB[(size_t)(j0 + c) * (B_ * H_) + b_idx * 1024 + x] =
            make_float2(A, Bv);
      }
    }
  }
#undef STAGE
#undef LD_A
#undef LD_B
#undef MFMA_Q
#undef PH_BAR
#undef PH_END
#undef PH_END_VM
}

// ---------------------------------------------------------------------------
// Fused carry + apply: each block recomputes its chunk's carry by walking the
// sAB prefix [0, j) for its 2 channels, then applies the chunk reading the
// PRE-COMPUTED (ca,cb) pairs from gh (packed layout: ca at col 32g+u,
// cb at col 32g+16+u for channel 16g+u).
//
// ALIASING NOTE: rin may equal rout (in-place residual for l>=1) -> not
// __restrict__; the t-loop is hand-pipelined in groups of 8 (all loads of a
// group before any store) so store->load serialization is avoided while
// staying exact-aliasing-safe.
// ---------------------------------------------------------------------------
__global__ __launch_bounds__(256)
void scan_apply(const bf16* __restrict__ gh, const float2* __restrict__ sAB,
                const float* __restrict__ hprev,
                const float* rin, float* rout, bf16* __restrict__ gout,
                float* __restrict__ finals) {
  const int tx = threadIdx.x, bx = blockIdx.x;
  const int half = bx & 1, b = (bx >> 1) & 7, j = bx >> 4;
  const int h = half * 512 + tx * 2;           // even channel
  const int c = b * 1024 + h;
  const int pc = h + ((h >> 4) << 4);          // packed ca col = 32g+u

  float h0, h1;
  {
    const float2 hp = *(const float2*)(hprev + c);
    h0 = g_of(hp.x); h1 = g_of(hp.y);
  }
  for (int jj = 0; jj < j; ++jj) {
    const float4 ab = *(const float4*)(sAB + (size_t)jj * (B_ * H_) + c);
    h0 = ab.x * h0 + ab.y;
    h1 = ab.z * h1 + ab.w;
  }

  const size_t rbase = ((size_t)(b * S_ + j * CLEN_)) * H_ + h;
  const bf16* gbase = gh + ((size_t)(b * S_ + j * CLEN_)) * N_ + pc;
#pragma unroll 1
  for (int tt = 0; tt < CLEN_; tt += 8) {
    bf16x2 av[8], bv[8];
    float2 rv[8];
#pragma unroll
    for (int u = 0; u < 8; ++u) {
      const size_t t = (size_t)(tt + u);
      av[u] = *(const bf16x2*)(gbase + t * N_);        // (ca_h, ca_h+1)
      bv[u] = *(const bf16x2*)(gbase + t * N_ + 16);   // (cb_h, cb_h+1)
      rv[u] = *(const float2*)(rin + rbase + t * H_);
    }
#pragma unroll
    for (int u = 0; u < 8; ++u) {
      const size_t t = (size_t)(tt + u);
      h0 = (float)av[u][0] * h0 + (float)bv[u][0];
      h1 = (float)av[u][1] * h1 + (float)bv[u][1];
      const float r0 = h0 + rv[u].x;
      const float r1 = h1 + rv[u].y;
      *(float2*)(rout + rbase + t * H_) = make_float2(r0, r1);
      if (gout) {
        bf16x2 o;
        o[0] = (__bf16)r0; o[1] = (__bf16)r1;
        *(bf16x2*)(gout + rbase + t * H_) = o;
      }
    }
  }
  if (j == CHUNKS_ - 1)
    *(float2*)(finals + c) = make_float2(h0, h1);
}

// ---------------------------------------------------------------------------
extern "C" void kernel_launch(void* const* d_in, const int* in_sizes, int n_in,
                              void* d_out, int out_size, void* d_ws,
                              size_t ws_size, hipStream_t stream) {
  const float* x  = (const float*)d_in[0];
  const float* h0 = (const float*)d_in[1];  // (L,B,1,H)
  const float* W0 = (const float*)d_in[2];  // (2H, D)
  const float* b0 = (const float*)d_in[3];  // (2H,)
  const float* Wl = (const float*)d_in[4];  // (L-1, 2H, H)
  const float* bl = (const float*)d_in[5];  // (L-1, 2H)
  float* out    = (float*)d_out;            // (B,S,H) residual stream, in-place
  float* finals = out + (size_t)M_ * H_;    // (L,B,1,H)

  char* ws = (char*)d_ws;
  bf16* gh   = (bf16*)ws;                   // 64 MB: (M_, 2H) (ca,cb) packed
  bf16* bufA = (bf16*)(ws + (64u << 20));   // 32 MB: bf16 A for current layer

  const bool wide = ws_size >= ((size_t)115 << 20);
  // wide:  wb = 4 packed weight mats @96 (16 MB), sAB @112 (2 MB)
  // narrow: per-layer packed weights @96 (4 MB), sAB @101 (2 MB)
  bf16*   wb  = (bf16*)(ws + (96u << 20));
  float2* sAB = (float2*)(ws + ((wide ? 112u : 101u) << 20));

  // x -> bf16 into bufA (layer-0 A). 16M elems.
  cvt_f32_bf16<<<dim3(M_ * K_ / 8 / 256), 256, 0, stream>>>(x, bufA, (long)M_ * K_);
  if (wide) {  // pack+convert all weights once
    cvt_pack_w<<<dim3(N_ * K_ / 8 / 256), 256, 0, stream>>>(W0, wb, 1);
    cvt_pack_w<<<dim3(3 * N_ * K_ / 8 / 256), 256, 0, stream>>>(
        Wl, wb + (size_t)N_ * K_, 3);
  }

  for (int l = 0; l < 4; ++l) {
    const float* Wf = (l == 0) ? W0 : Wl + (size_t)(l - 1) * N_ * K_;
    const float* bi = (l == 0) ? b0 : bl + (size_t)(l - 1) * N_;
    bf16* wl_ptr;
    if (wide) {
      wl_ptr = wb + (size_t)l * N_ * K_;
    } else {
      cvt_pack_w<<<dim3(N_ * K_ / 8 / 256), 256, 0, stream>>>(Wf, wb, 1);
      wl_ptr = wb;
    }
    gemm256<<<dim3(512), 512, 0, stream>>>(bufA, wl_ptr, bi, gh, sAB);
    scan_apply<<<dim3(512), 256, 0, stream>>>(
        gh, sAB, h0 + (size_t)l * B_ * H_, (l == 0) ? x : out, out,
        (l == 3) ? nullptr : bufA, finals + (size_t)l * B_ * H_);
  }
}